// Round 17
// baseline (93.121 us; speedup 1.0000x reference)
//
#include <hip/hip_runtime.h>

// GQA attention fused pipeline for MI355X (gfx950).
// cvt(fused) -> GEMM-QKV with FUSED RoPE/scatter/V-transpose epilogue
// (writes Q row-major + K,V fragment-major directly from accumulators)
// -> flash attention (LDS-shared K/V, static-max softmax) -> GEMM(out, BN=64).
// EXACT reversion to the round-14 kernel (last passing configuration).

typedef __bf16 bf16x8 __attribute__((ext_vector_type(8)));
typedef float f32x4 __attribute__((ext_vector_type(4)));
typedef float f32x16 __attribute__((ext_vector_type(16)));
typedef int i32x4 __attribute__((ext_vector_type(4)));
typedef unsigned short ushort4v __attribute__((ext_vector_type(4)));
typedef unsigned short ushort8v __attribute__((ext_vector_type(8)));
typedef unsigned short u16;
typedef unsigned int u32;

#define DEVINL __device__ __forceinline__

DEVINL float bf2f(u16 u) {
  unsigned int x = ((unsigned int)u) << 16;
  return __builtin_bit_cast(float, x);
}
DEVINL u16 f2bf(float f) {  // RTNE
  unsigned int x = __builtin_bit_cast(unsigned int, f);
  x += 0x7fffu + ((x >> 16) & 1u);
  return (u16)(x >> 16);
}
// raw 2^x — single v_exp_f32
DEVINL float exp2r(float x) {
  float r;
  asm("v_exp_f32 %0, %1" : "=v"(r) : "v"(x));
  return r;
}
// async global->LDS, 16B/lane; LDS dest = wave-uniform base + lane*16
DEVINL void gld16(const u16* g, u16* l) {
  __builtin_amdgcn_global_load_lds(
      (const __attribute__((address_space(1))) void*)g,
      (__attribute__((address_space(3))) void*)l, 16, 0, 0);
}

constexpr int Bb = 2, Tt = 2048, Dd = 1024, QH = 16, KVH = 4, HD = 64;
constexpr float SCALE_L2E = 0.125f * 1.44269504088896340736f;
constexpr int KVSZ = 131072;  // per-(b,kvh) fragment-major K/V extent (elems)

// ---------------------------------------------------------------- fused convert
__global__ void cvt_all(const float* __restrict__ x, const float* __restrict__ Wq,
                        const float* __restrict__ Wkv, const float* __restrict__ Wo,
                        u16* __restrict__ xb, u16* __restrict__ wqkv,
                        u16* __restrict__ wob) {
  int i = blockIdx.x * 256 + threadIdx.x;  // grid covers 1,703,936 float4s exactly
  const float* src;
  u16* dst;
  if (i < 1048576) {
    src = x; dst = xb;
  } else if (i < 1310720) {
    src = Wq - (size_t)1048576 * 4; dst = wqkv - (size_t)1048576 * 4;
  } else if (i < 1441792) {
    src = Wkv - (size_t)1310720 * 4; dst = wqkv + (size_t)1024 * 1024 - (size_t)1310720 * 4;
  } else {
    src = Wo - (size_t)1441792 * 4; dst = wob - (size_t)1441792 * 4;
  }
  float4 v = reinterpret_cast<const float4*>(src)[i];
  ushort4v o = {f2bf(v.x), f2bf(v.y), f2bf(v.z), f2bf(v.w)};
  *reinterpret_cast<ushort4v*>(dst + (size_t)i * 4) = o;
}

// ---------------------------------------------------------------- QKV GEMM + fused RoPE/scatter
// C = xb(4096,1024) @ wqkv(1536,1024)^T. Each block's 64-col range is entirely
// one q-head / k-half / v-half. Epilogue applies RoPE in f32 via shfl_xor(1)
// (pair (d,d+1) = adjacent lanes) and writes Q row-major (pre-scaled),
// K & V fragment-major — Pbuf round-trip and rope_vt kernel eliminated.
__global__ __launch_bounds__(256) void gemm_qkv(const u16* __restrict__ A,
                                                const u16* __restrict__ Bw,
                                                const float* __restrict__ cosT,
                                                const float* __restrict__ sinT,
                                                u16* __restrict__ Qb,
                                                u16* __restrict__ Kf,
                                                u16* __restrict__ Vf) {
  constexpr int K = 1024;
  __shared__ alignas(16) u16 lA[128 * 64];
  __shared__ alignas(16) u16 lB[64 * 64];
  const int tid = threadIdx.x;
  const int w = tid >> 6, lane = tid & 63;
  const int r16 = lane & 15, g4 = lane >> 4;
  const int row0 = blockIdx.y * 128, col0 = blockIdx.x * 64;
  const int sr = tid >> 3, sc = tid & 7;
  const int NT = K >> 6;

  bf16x8 ra[4], rb[2];
  f32x4 acc[4][2];
#pragma unroll
  for (int i = 0; i < 4; ++i)
#pragma unroll
    for (int j = 0; j < 2; ++j) acc[i][j] = f32x4{0.f, 0.f, 0.f, 0.f};

  const int wm = (w >> 1) * 64, wn2 = (w & 1) * 32;

#pragma unroll
  for (int i = 0; i < 4; ++i) {
    int r = i * 32 + sr;
    ra[i] = *reinterpret_cast<const bf16x8*>(A + (size_t)(row0 + r) * K + sc * 8);
  }
#pragma unroll
  for (int i = 0; i < 2; ++i) {
    int r = i * 32 + sr;
    rb[i] = *reinterpret_cast<const bf16x8*>(Bw + (size_t)(col0 + r) * K + sc * 8);
  }

  for (int kt = 0; kt < NT; ++kt) {
    __syncthreads();
#pragma unroll
    for (int i = 0; i < 4; ++i) {
      int r = i * 32 + sr;
      int c = (sc ^ (r & 7)) * 8;
      *reinterpret_cast<bf16x8*>(&lA[r * 64 + c]) = ra[i];
    }
#pragma unroll
    for (int i = 0; i < 2; ++i) {
      int r = i * 32 + sr;
      int c = (sc ^ (r & 7)) * 8;
      *reinterpret_cast<bf16x8*>(&lB[r * 64 + c]) = rb[i];
    }
    __syncthreads();
    if (kt + 1 < NT) {
      int k0 = (kt + 1) << 6;
#pragma unroll
      for (int i = 0; i < 4; ++i) {
        int r = i * 32 + sr;
        ra[i] = *reinterpret_cast<const bf16x8*>(A + (size_t)(row0 + r) * K + k0 + sc * 8);
      }
#pragma unroll
      for (int i = 0; i < 2; ++i) {
        int r = i * 32 + sr;
        rb[i] = *reinterpret_cast<const bf16x8*>(Bw + (size_t)(col0 + r) * K + k0 + sc * 8);
      }
    }
#pragma unroll
    for (int kk = 0; kk < 2; ++kk) {
      bf16x8 af[4], bfr[2];
#pragma unroll
      for (int mf = 0; mf < 4; ++mf) {
        int r = wm + mf * 16 + r16;
        int c = ((kk * 4 + g4) ^ (r & 7)) * 8;
        af[mf] = *reinterpret_cast<const bf16x8*>(&lA[r * 64 + c]);
      }
#pragma unroll
      for (int nf = 0; nf < 2; ++nf) {
        int r = wn2 + nf * 16 + r16;
        int c = ((kk * 4 + g4) ^ (r & 7)) * 8;
        bfr[nf] = *reinterpret_cast<const bf16x8*>(&lB[r * 64 + c]);
      }
#pragma unroll
      for (int mf = 0; mf < 4; ++mf)
#pragma unroll
        for (int nf = 0; nf < 2; ++nf)
          acc[mf][nf] =
              __builtin_amdgcn_mfma_f32_16x16x32_bf16(af[mf], bfr[nf], acc[mf][nf], 0, 0, 0);
    }
  }

  // ---- fused epilogue: rope + scatter straight from f32 accumulators ----
  // pair partner (d xor 1) is the adjacent lane (d parity == r16 parity)
  const float psign = (r16 & 1) ? 1.f : -1.f;
  if (col0 < 1024) {  // ---- Q head: rope, pre-scale, row-major ----
    const int hq = col0 >> 6;
#pragma unroll
    for (int nf = 0; nf < 2; ++nf) {
      const int d = wn2 + nf * 16 + r16;
#pragma unroll
      for (int mf = 0; mf < 4; ++mf)
#pragma unroll
        for (int r = 0; r < 4; ++r) {
          int bt = row0 + wm + mf * 16 + g4 * 4 + r;
          int b = bt >> 11, t = bt & 2047;
          float v = acc[mf][nf][r];
          float pv = __shfl_xor(v, 1);
          float c = cosT[t * 64 + d] * SCALE_L2E;
          float s = sinT[t * 64 + d] * SCALE_L2E;
          float o = v * c + psign * pv * s;
          Qb[((size_t)(b * QH + hq) * Tt + t) * HD + d] = f2bf(o);
        }
    }
  } else {
    const int kvcol = col0 - 1024;
    const int kvh = kvcol >> 7, isv = (kvcol >> 6) & 1;
    if (!isv) {  // ---- K: rope (unscaled), fragment-major ----
#pragma unroll
      for (int nf = 0; nf < 2; ++nf) {
        const int d = wn2 + nf * 16 + r16;
        const int kf = d >> 4, h8 = (d >> 3) & 1, j = d & 7;
#pragma unroll
        for (int mf = 0; mf < 4; ++mf)
#pragma unroll
          for (int r = 0; r < 4; ++r) {
            int bt = row0 + wm + mf * 16 + g4 * 4 + r;
            int b = bt >> 11, t = bt & 2047;
            float v = acc[mf][nf][r];
            float pv = __shfl_xor(v, 1);
            float c = cosT[t * 64 + d], s = sinT[t * 64 + d];
            float o = v * c + psign * pv * s;
            size_t bh = (size_t)(b * KVH + kvh);
            Kf[bh * KVSZ + ((t >> 5) * 4 + kf) * 512 + (h8 * 32 + (t & 31)) * 8 + j] = f2bf(o);
          }
      }
    } else {  // ---- V: straight cast, fragment-major transpose ----
#pragma unroll
      for (int nf = 0; nf < 2; ++nf) {
        const int d = wn2 + nf * 16 + r16;
        const int df = d >> 5, l = d & 31;
#pragma unroll
        for (int mf = 0; mf < 4; ++mf)
#pragma unroll
          for (int r = 0; r < 4; ++r) {
            int bt = row0 + wm + mf * 16 + g4 * 4 + r;
            int b = bt >> 11, t = bt & 2047;
            size_t bh = (size_t)(b * KVH + kvh);
            size_t addr = bh * KVSZ +
                          (((t >> 6) * 2 + df) * 4 + ((t >> 4) & 3)) * 512 +
                          (((t >> 3) & 1) * 32 + l) * 8 + (t & 7);
            Vf[addr] = f2bf(acc[mf][nf][r]);
          }
      }
    }
  }
}

// ---------------------------------------------------------------- plain GEMM (out-proj)
template <bool OUT_F32, int BNF>
__global__ __launch_bounds__(256) void gemm_bt(const u16* __restrict__ A,
                                               const u16* __restrict__ Bw,
                                               void* __restrict__ Cout, int M, int N, int K) {
  __shared__ alignas(16) u16 lA[128 * 64];
  __shared__ alignas(16) u16 lB[BNF * 32 * 64];
  const int tid = threadIdx.x;
  const int w = tid >> 6, lane = tid & 63;
  const int r16 = lane & 15, g4 = lane >> 4;
  const int row0 = blockIdx.y * 128, col0 = blockIdx.x * (BNF * 32);
  const int sr = tid >> 3, sc = tid & 7;
  const int NT = K >> 6;

  bf16x8 ra[4], rb[BNF];
  f32x4 acc[4][BNF];
#pragma unroll
  for (int i = 0; i < 4; ++i)
#pragma unroll
    for (int j = 0; j < BNF; ++j) acc[i][j] = f32x4{0.f, 0.f, 0.f, 0.f};

  const int wm = (w >> 1) * 64, wn2 = (w & 1) * (BNF * 16);

#pragma unroll
  for (int i = 0; i < 4; ++i) {
    int r = i * 32 + sr;
    ra[i] = *reinterpret_cast<const bf16x8*>(A + (size_t)(row0 + r) * K + sc * 8);
  }
#pragma unroll
  for (int i = 0; i < BNF; ++i) {
    int r = i * 32 + sr;
    rb[i] = *reinterpret_cast<const bf16x8*>(Bw + (size_t)(col0 + r) * K + sc * 8);
  }

  for (int kt = 0; kt < NT; ++kt) {
    __syncthreads();
#pragma unroll
    for (int i = 0; i < 4; ++i) {
      int r = i * 32 + sr;
      int c = (sc ^ (r & 7)) * 8;
      *reinterpret_cast<bf16x8*>(&lA[r * 64 + c]) = ra[i];
    }
#pragma unroll
    for (int i = 0; i < BNF; ++i) {
      int r = i * 32 + sr;
      int c = (sc ^ (r & 7)) * 8;
      *reinterpret_cast<bf16x8*>(&lB[r * 64 + c]) = rb[i];
    }
    __syncthreads();
    if (kt + 1 < NT) {
      int k0 = (kt + 1) << 6;
#pragma unroll
      for (int i = 0; i < 4; ++i) {
        int r = i * 32 + sr;
        ra[i] = *reinterpret_cast<const bf16x8*>(A + (size_t)(row0 + r) * K + k0 + sc * 8);
      }
#pragma unroll
      for (int i = 0; i < BNF; ++i) {
        int r = i * 32 + sr;
        rb[i] = *reinterpret_cast<const bf16x8*>(Bw + (size_t)(col0 + r) * K + k0 + sc * 8);
      }
    }
#pragma unroll
    for (int kk = 0; kk < 2; ++kk) {
      bf16x8 af[4], bfr[BNF];
#pragma unroll
      for (int mf = 0; mf < 4; ++mf) {
        int r = wm + mf * 16 + r16;
        int c = ((kk * 4 + g4) ^ (r & 7)) * 8;
        af[mf] = *reinterpret_cast<const bf16x8*>(&lA[r * 64 + c]);
      }
#pragma unroll
      for (int nf = 0; nf < BNF; ++nf) {
        int r = wn2 + nf * 16 + r16;
        int c = ((kk * 4 + g4) ^ (r & 7)) * 8;
        bfr[nf] = *reinterpret_cast<const bf16x8*>(&lB[r * 64 + c]);
      }
#pragma unroll
      for (int mf = 0; mf < 4; ++mf)
#pragma unroll
        for (int nf = 0; nf < BNF; ++nf)
          acc[mf][nf] =
              __builtin_amdgcn_mfma_f32_16x16x32_bf16(af[mf], bfr[nf], acc[mf][nf], 0, 0, 0);
    }
  }

#pragma unroll
  for (int mf = 0; mf < 4; ++mf)
#pragma unroll
    for (int nf = 0; nf < BNF; ++nf)
#pragma unroll
      for (int r = 0; r < 4; ++r) {
        size_t row = (size_t)(row0 + wm + mf * 16 + g4 * 4 + r);
        size_t col = (size_t)(col0 + wn2 + nf * 16 + r16);
        float v = acc[mf][nf][r];
        if (OUT_F32)
          reinterpret_cast<float*>(Cout)[row * N + col] = v;
        else
          reinterpret_cast<u16*>(Cout)[row * N + col] = f2bf(v);
      }
}

// ---------------------------------------------------------------- flash attention (r11/r14, proven)
__global__ __launch_bounds__(512, 4) void attn_fwd10(const u16* __restrict__ Q,
                                                     const u16* __restrict__ Kf,
                                                     const u16* __restrict__ Vf,
                                                     u16* __restrict__ Oa) {
  __shared__ alignas(16) u16 arena[32768];
  const int tid = threadIdx.x;
  const int w = tid >> 6, lane = tid & 63;
  const int g = w & 3, spl = w >> 2;
  const int l31 = lane & 31, hi = lane >> 5;

  const int fid = blockIdx.x;
  const int xcd = fid & 7, idx = fid >> 3;  // xcd == (b,kvh)
  const int b = xcd >> 2, kvh = xcd & 3;
  const int h = kvh * 4 + g;
  const int t0 = idx * 32;
  const size_t bh = (size_t)(b * KVH + kvh);

  const int rg = w & 3;
  const int sv = rg & 1, isV = rg >> 1;
  const u16* gsrc = (isV ? Vf : Kf) + bh * KVSZ + sv * 65536 + spl * 2048 + lane * 8;
  const int ldst0 = isV * 16384 + sv * 4096 + spl * 2048;

  const u16* Qh = Q + ((size_t)(b * QH + h) * Tt + t0 + l31) * HD + hi * 8;
  bf16x8 qf[4];
#pragma unroll
  for (int kf = 0; kf < 4; ++kf)
    qf[kf] = *reinterpret_cast<const bf16x8*>(Qh + kf * 16);

  f32x16 oacc[2];
#pragma unroll
  for (int df = 0; df < 2; ++df)
#pragma unroll
    for (int r = 0; r < 16; ++r) oacc[df][r] = 0.f;
  float lp = 0.f;

#pragma unroll
  for (int i = 0; i < 4; ++i) gld16(gsrc + i * 512, &arena[ldst0 + i * 512]);
  __syncthreads();

  int cur = 0;
  for (int it = 0; it < 16; ++it) {
    if (it < 15) {
      const u16* gs = gsrc + (it + 1) * 4096;
      u16* ld = &arena[ldst0 + (cur ^ 1) * 8192];
#pragma unroll
      for (int i = 0; i < 4; ++i) gld16(gs + i * 512, ld + i * 512);
    }
    const int ktb = cur * 8192 + spl * 4096;
    const int vtb = 16384 + cur * 8192 + spl * 4096;

    f32x16 sacc[2];
#pragma unroll
    for (int sb = 0; sb < 2; ++sb) {
      bf16x8 kfr[4];
#pragma unroll
      for (int kf = 0; kf < 4; ++kf)
        kfr[kf] = *reinterpret_cast<const bf16x8*>(&arena[ktb + sb * 2048 + kf * 512 + lane * 8]);
#pragma unroll
      for (int r = 0; r < 16; ++r) sacc[sb][r] = 0.f;
      __builtin_amdgcn_s_setprio(1);
#pragma unroll
      for (int kf = 0; kf < 4; ++kf)
        sacc[sb] = __builtin_amdgcn_mfma_f32_32x32x16_bf16(kfr[kf], qf[kf], sacc[sb], 0, 0, 0);
      __builtin_amdgcn_s_setprio(0);
    }

    float a0 = 0.f, a1 = 0.f, a2 = 0.f, a3 = 0.f;
#pragma unroll
    for (int sb = 0; sb < 2; ++sb)
#pragma unroll
      for (int r = 0; r < 16; r += 4) {
        float e0 = exp2r(sacc[sb][r]);
        float e1 = exp2r(sacc[sb][r + 1]);
        float e2 = exp2r(sacc[sb][r + 2]);
        float e3 = exp2r(sacc[sb][r + 3]);
        sacc[sb][r] = e0; sacc[sb][r + 1] = e1; sacc[sb][r + 2] = e2; sacc[sb][r + 3] = e3;
        a0 += e0; a1 += e1; a2 += e2; a3 += e3;
      }
    lp += (a0 + a1) + (a2 + a3);

    bf16x8 pf[2][2];
#pragma unroll
    for (int sb = 0; sb < 2; ++sb) {
      u32 pw[8];
#pragma unroll
      for (int r2 = 0; r2 < 8; ++r2) {
        u32 o;
        asm("v_cvt_pk_bf16_f32 %0, %1, %2"
            : "=v"(o)
            : "v"(sacc[sb][2 * r2]), "v"(sacc[sb][2 * r2 + 1]));
        pw[r2] = o;
      }
      u32 fw[2][4];
#pragma unroll
      for (int pp = 0; pp < 4; ++pp) {
        int ks = pp >> 1, o = pp & 1;
        u32 a = pw[ks * 4 + o], bq = pw[ks * 4 + o + 2];
        asm("v_permlane32_swap_b32 %0, %1" : "+v"(a), "+v"(bq));
        fw[ks][o] = a;
        fw[ks][o + 2] = bq;
      }
#pragma unroll
      for (int ks = 0; ks < 2; ++ks) {
        i32x4 iv = {(int)fw[ks][0], (int)fw[ks][1], (int)fw[ks][2], (int)fw[ks][3]};
        pf[sb][ks] = __builtin_bit_cast(bf16x8, iv);
      }
    }

    __builtin_amdgcn_s_setprio(1);
#pragma unroll
    for (int df = 0; df < 2; ++df)
#pragma unroll
      for (int sb = 0; sb < 2; ++sb)
#pragma unroll
        for (int ks = 0; ks < 2; ++ks) {
          bf16x8 vfr = *reinterpret_cast<const bf16x8*>(
              &arena[vtb + (df * 4 + sb * 2 + ks) * 512 + lane * 8]);
          oacc[df] = __builtin_amdgcn_mfma_f32_32x32x16_bf16(vfr, pf[sb][ks], oacc[df], 0, 0, 0);
        }
    __builtin_amdgcn_s_setprio(0);

    __syncthreads();
    cur ^= 1;
  }

  lp += __shfl_xor(lp, 32);
  float* cb = reinterpret_cast<float*>(arena) + ((size_t)g * 32 + l31) * 66;
  if (spl == 1) {
#pragma unroll
    for (int df = 0; df < 2; ++df)
#pragma unroll
      for (int r = 0; r < 16; ++r) {
        int d = df * 32 + (r & 3) + 8 * (r >> 2) + 4 * hi;
        cb[d] = oacc[df][r];
      }
    if (hi == 0) cb[64] = lp;
  }
  __syncthreads();
  if (spl == 0) {
    lp += cb[64];
    float linv = 1.0f / lp;
    u16* otg = arena + 17408 + g * 2304;
#pragma unroll
    for (int df = 0; df < 2; ++df)
#pragma unroll
      for (int r = 0; r < 16; ++r) {
        int d = df * 32 + (r & 3) + 8 * (r >> 2) + 4 * hi;
        otg[l31 * 72 + d] = f2bf((oacc[df][r] + cb[d]) * linv);
      }
  }
  __syncthreads();
  if (spl == 0) {
    const u16* otg = arena + 17408 + g * 2304;
    int tr = lane >> 1, dblk = (lane & 1) * 32;
    u16* gdst = Oa + ((size_t)(b * Tt + t0 + tr)) * Dd + h * HD + dblk;
#pragma unroll
    for (int c = 0; c < 4; ++c) {
      ushort8v vv = *reinterpret_cast<const ushort8v*>(&otg[tr * 72 + dblk + c * 8]);
      *reinterpret_cast<ushort8v*>(gdst + c * 8) = vv;
    }
  }
}

// ---------------------------------------------------------------- launch
extern "C" void kernel_launch(void* const* d_in, const int* in_sizes, int n_in, void* d_out,
                              int out_size, void* d_ws, size_t ws_size, hipStream_t stream) {
  (void)in_sizes; (void)n_in; (void)out_size; (void)ws_size;
  const float* x = (const float*)d_in[0];
  const float* cosT = (const float*)d_in[1];
  const float* sinT = (const float*)d_in[2];
  const float* Wq = (const float*)d_in[3];
  const float* Wkv = (const float*)d_in[4];
  const float* Wo = (const float*)d_in[5];

  char* p = (char*)d_ws;
  u16* xb = (u16*)p;   p += (size_t)4096 * 1024 * 2;
  u16* wqkv = (u16*)p; p += (size_t)1536 * 1024 * 2;
  u16* wob = (u16*)p;  p += (size_t)1024 * 1024 * 2;
  u16* Pbuf = (u16*)p; p += (size_t)4096 * 1536 * 2;
  u16* Qb = (u16*)p;   p += (size_t)Bb * QH * Tt * HD * 2;
  u16* Kbuf = (u16*)p; p += (size_t)Bb * KVH * Tt * HD * 2;
  u16* Vfb = (u16*)p;  p += (size_t)Bb * KVH * HD * Tt * 2;
  u16* Ob = Pbuf;  // attention-output staging (bf16), feeds gemm2

  cvt_all<<<6656, 256, 0, stream>>>(x, Wq, Wkv, Wo, xb, wqkv, wob);
  gemm_qkv<<<dim3(24, 32), 256, 0, stream>>>(xb, wqkv, cosT, sinT, Qb, Kbuf, Vfb);
  attn_fwd10<<<512, 512, 0, stream>>>(Qb, Kbuf, Vfb, Ob);
  gemm_bt<true, 2><<<dim3(16, 32), 256, 0, stream>>>(Ob, wob, d_out, 4096, 1024, 1024);
}

// Round 18
// 92.756 us; speedup vs baseline: 1.0039x; 1.0039x over previous
//
#include <hip/hip_runtime.h>

// GQA attention fused pipeline for MI355X (gfx950).
// cvt(fused) -> GEMM-QKV (fused RoPE/scatter/V-transpose epilogue, XCD-swizzled
// grid) -> flash attention (LDS-shared K/V, static-max softmax) -> GEMM(out,
// BN=64, XCD-swizzled grid). Identical to round-17 except the two GEMM grids
// are 1-D with a bijective XCD swizzle: each XCD owns whole row-panels so the
// A-panel is fetched into exactly one L2 (T1; 768=8x4x24, 512=8x4x16).

typedef __bf16 bf16x8 __attribute__((ext_vector_type(8)));
typedef float f32x4 __attribute__((ext_vector_type(4)));
typedef float f32x16 __attribute__((ext_vector_type(16)));
typedef int i32x4 __attribute__((ext_vector_type(4)));
typedef unsigned short ushort4v __attribute__((ext_vector_type(4)));
typedef unsigned short ushort8v __attribute__((ext_vector_type(8)));
typedef unsigned short u16;
typedef unsigned int u32;

#define DEVINL __device__ __forceinline__

DEVINL float bf2f(u16 u) {
  unsigned int x = ((unsigned int)u) << 16;
  return __builtin_bit_cast(float, x);
}
DEVINL u16 f2bf(float f) {  // RTNE
  unsigned int x = __builtin_bit_cast(unsigned int, f);
  x += 0x7fffu + ((x >> 16) & 1u);
  return (u16)(x >> 16);
}
// raw 2^x — single v_exp_f32
DEVINL float exp2r(float x) {
  float r;
  asm("v_exp_f32 %0, %1" : "=v"(r) : "v"(x));
  return r;
}
// async global->LDS, 16B/lane; LDS dest = wave-uniform base + lane*16
DEVINL void gld16(const u16* g, u16* l) {
  __builtin_amdgcn_global_load_lds(
      (const __attribute__((address_space(1))) void*)g,
      (__attribute__((address_space(3))) void*)l, 16, 0, 0);
}

constexpr int Bb = 2, Tt = 2048, Dd = 1024, QH = 16, KVH = 4, HD = 64;
constexpr float SCALE_L2E = 0.125f * 1.44269504088896340736f;
constexpr int KVSZ = 131072;  // per-(b,kvh) fragment-major K/V extent (elems)

// ---------------------------------------------------------------- fused convert
__global__ void cvt_all(const float* __restrict__ x, const float* __restrict__ Wq,
                        const float* __restrict__ Wkv, const float* __restrict__ Wo,
                        u16* __restrict__ xb, u16* __restrict__ wqkv,
                        u16* __restrict__ wob) {
  int i = blockIdx.x * 256 + threadIdx.x;  // grid covers 1,703,936 float4s exactly
  const float* src;
  u16* dst;
  if (i < 1048576) {
    src = x; dst = xb;
  } else if (i < 1310720) {
    src = Wq - (size_t)1048576 * 4; dst = wqkv - (size_t)1048576 * 4;
  } else if (i < 1441792) {
    src = Wkv - (size_t)1310720 * 4; dst = wqkv + (size_t)1024 * 1024 - (size_t)1310720 * 4;
  } else {
    src = Wo - (size_t)1441792 * 4; dst = wob - (size_t)1441792 * 4;
  }
  float4 v = reinterpret_cast<const float4*>(src)[i];
  ushort4v o = {f2bf(v.x), f2bf(v.y), f2bf(v.z), f2bf(v.w)};
  *reinterpret_cast<ushort4v*>(dst + (size_t)i * 4) = o;
}

// ---------------------------------------------------------------- QKV GEMM + fused RoPE/scatter
// 1-D grid 768 = 8 XCD x 4 row-panels x 24 col-blocks; xcd = bid&7 owns
// panels [xcd*4, xcd*4+4) so each A-panel lives in exactly one XCD L2.
__global__ __launch_bounds__(256) void gemm_qkv(const u16* __restrict__ A,
                                                const u16* __restrict__ Bw,
                                                const float* __restrict__ cosT,
                                                const float* __restrict__ sinT,
                                                u16* __restrict__ Qb,
                                                u16* __restrict__ Kf,
                                                u16* __restrict__ Vf) {
  constexpr int K = 1024;
  __shared__ alignas(16) u16 lA[128 * 64];
  __shared__ alignas(16) u16 lB[64 * 64];
  const int tid = threadIdx.x;
  const int w = tid >> 6, lane = tid & 63;
  const int r16 = lane & 15, g4 = lane >> 4;
  // XCD swizzle (bijective: 768 = 8*96, 96 = 4 panels * 24 cols)
  const int lin = blockIdx.x;
  const int xcd = lin & 7, sub = lin >> 3;
  const int row0 = (xcd * 4 + sub / 24) * 128, col0 = (sub % 24) * 64;
  const int sr = tid >> 3, sc = tid & 7;
  const int NT = K >> 6;

  bf16x8 ra[4], rb[2];
  f32x4 acc[4][2];
#pragma unroll
  for (int i = 0; i < 4; ++i)
#pragma unroll
    for (int j = 0; j < 2; ++j) acc[i][j] = f32x4{0.f, 0.f, 0.f, 0.f};

  const int wm = (w >> 1) * 64, wn2 = (w & 1) * 32;

#pragma unroll
  for (int i = 0; i < 4; ++i) {
    int r = i * 32 + sr;
    ra[i] = *reinterpret_cast<const bf16x8*>(A + (size_t)(row0 + r) * K + sc * 8);
  }
#pragma unroll
  for (int i = 0; i < 2; ++i) {
    int r = i * 32 + sr;
    rb[i] = *reinterpret_cast<const bf16x8*>(Bw + (size_t)(col0 + r) * K + sc * 8);
  }

  for (int kt = 0; kt < NT; ++kt) {
    __syncthreads();
#pragma unroll
    for (int i = 0; i < 4; ++i) {
      int r = i * 32 + sr;
      int c = (sc ^ (r & 7)) * 8;
      *reinterpret_cast<bf16x8*>(&lA[r * 64 + c]) = ra[i];
    }
#pragma unroll
    for (int i = 0; i < 2; ++i) {
      int r = i * 32 + sr;
      int c = (sc ^ (r & 7)) * 8;
      *reinterpret_cast<bf16x8*>(&lB[r * 64 + c]) = rb[i];
    }
    __syncthreads();
    if (kt + 1 < NT) {
      int k0 = (kt + 1) << 6;
#pragma unroll
      for (int i = 0; i < 4; ++i) {
        int r = i * 32 + sr;
        ra[i] = *reinterpret_cast<const bf16x8*>(A + (size_t)(row0 + r) * K + k0 + sc * 8);
      }
#pragma unroll
      for (int i = 0; i < 2; ++i) {
        int r = i * 32 + sr;
        rb[i] = *reinterpret_cast<const bf16x8*>(Bw + (size_t)(col0 + r) * K + k0 + sc * 8);
      }
    }
#pragma unroll
    for (int kk = 0; kk < 2; ++kk) {
      bf16x8 af[4], bfr[2];
#pragma unroll
      for (int mf = 0; mf < 4; ++mf) {
        int r = wm + mf * 16 + r16;
        int c = ((kk * 4 + g4) ^ (r & 7)) * 8;
        af[mf] = *reinterpret_cast<const bf16x8*>(&lA[r * 64 + c]);
      }
#pragma unroll
      for (int nf = 0; nf < 2; ++nf) {
        int r = wn2 + nf * 16 + r16;
        int c = ((kk * 4 + g4) ^ (r & 7)) * 8;
        bfr[nf] = *reinterpret_cast<const bf16x8*>(&lB[r * 64 + c]);
      }
#pragma unroll
      for (int mf = 0; mf < 4; ++mf)
#pragma unroll
        for (int nf = 0; nf < 2; ++nf)
          acc[mf][nf] =
              __builtin_amdgcn_mfma_f32_16x16x32_bf16(af[mf], bfr[nf], acc[mf][nf], 0, 0, 0);
    }
  }

  // ---- fused epilogue: rope + scatter straight from f32 accumulators ----
  const float psign = (r16 & 1) ? 1.f : -1.f;
  if (col0 < 1024) {  // Q head: rope, pre-scale, row-major
    const int hq = col0 >> 6;
#pragma unroll
    for (int nf = 0; nf < 2; ++nf) {
      const int d = wn2 + nf * 16 + r16;
#pragma unroll
      for (int mf = 0; mf < 4; ++mf)
#pragma unroll
        for (int r = 0; r < 4; ++r) {
          int bt = row0 + wm + mf * 16 + g4 * 4 + r;
          int b = bt >> 11, t = bt & 2047;
          float v = acc[mf][nf][r];
          float pv = __shfl_xor(v, 1);
          float c = cosT[t * 64 + d] * SCALE_L2E;
          float s = sinT[t * 64 + d] * SCALE_L2E;
          float o = v * c + psign * pv * s;
          Qb[((size_t)(b * QH + hq) * Tt + t) * HD + d] = f2bf(o);
        }
    }
  } else {
    const int kvcol = col0 - 1024;
    const int kvh = kvcol >> 7, isv = (kvcol >> 6) & 1;
    if (!isv) {  // K: rope (unscaled), fragment-major
#pragma unroll
      for (int nf = 0; nf < 2; ++nf) {
        const int d = wn2 + nf * 16 + r16;
        const int kf = d >> 4, h8 = (d >> 3) & 1, j = d & 7;
#pragma unroll
        for (int mf = 0; mf < 4; ++mf)
#pragma unroll
          for (int r = 0; r < 4; ++r) {
            int bt = row0 + wm + mf * 16 + g4 * 4 + r;
            int b = bt >> 11, t = bt & 2047;
            float v = acc[mf][nf][r];
            float pv = __shfl_xor(v, 1);
            float c = cosT[t * 64 + d], s = sinT[t * 64 + d];
            float o = v * c + psign * pv * s;
            size_t bh = (size_t)(b * KVH + kvh);
            Kf[bh * KVSZ + ((t >> 5) * 4 + kf) * 512 + (h8 * 32 + (t & 31)) * 8 + j] = f2bf(o);
          }
      }
    } else {  // V: straight cast, fragment-major transpose
#pragma unroll
      for (int nf = 0; nf < 2; ++nf) {
        const int d = wn2 + nf * 16 + r16;
        const int df = d >> 5, l = d & 31;
#pragma unroll
        for (int mf = 0; mf < 4; ++mf)
#pragma unroll
          for (int r = 0; r < 4; ++r) {
            int bt = row0 + wm + mf * 16 + g4 * 4 + r;
            int b = bt >> 11, t = bt & 2047;
            size_t bh = (size_t)(b * KVH + kvh);
            size_t addr = bh * KVSZ +
                          (((t >> 6) * 2 + df) * 4 + ((t >> 4) & 3)) * 512 +
                          (((t >> 3) & 1) * 32 + l) * 8 + (t & 7);
            Vf[addr] = f2bf(acc[mf][nf][r]);
          }
      }
    }
  }
}

// ---------------------------------------------------------------- plain GEMM (out-proj)
// 1-D grid; XCD swizzle: each XCD owns (M/128)/8 whole row-panels.
template <bool OUT_F32, int BNF>
__global__ __launch_bounds__(256) void gemm_bt(const u16* __restrict__ A,
                                               const u16* __restrict__ Bw,
                                               void* __restrict__ Cout, int M, int N, int K) {
  __shared__ alignas(16) u16 lA[128 * 64];
  __shared__ alignas(16) u16 lB[BNF * 32 * 64];
  const int tid = threadIdx.x;
  const int w = tid >> 6, lane = tid & 63;
  const int r16 = lane & 15, g4 = lane >> 4;
  const int cols = N / (BNF * 32);
  const int perx = (M / 128) / 8;  // row-panels per XCD
  const int lin = blockIdx.x;
  const int xcd = lin & 7, sub = lin >> 3;
  const int row0 = (xcd * perx + sub / cols) * 128, col0 = (sub % cols) * (BNF * 32);
  const int sr = tid >> 3, sc = tid & 7;
  const int NT = K >> 6;

  bf16x8 ra[4], rb[BNF];
  f32x4 acc[4][BNF];
#pragma unroll
  for (int i = 0; i < 4; ++i)
#pragma unroll
    for (int j = 0; j < BNF; ++j) acc[i][j] = f32x4{0.f, 0.f, 0.f, 0.f};

  const int wm = (w >> 1) * 64, wn2 = (w & 1) * (BNF * 16);

#pragma unroll
  for (int i = 0; i < 4; ++i) {
    int r = i * 32 + sr;
    ra[i] = *reinterpret_cast<const bf16x8*>(A + (size_t)(row0 + r) * K + sc * 8);
  }
#pragma unroll
  for (int i = 0; i < BNF; ++i) {
    int r = i * 32 + sr;
    rb[i] = *reinterpret_cast<const bf16x8*>(Bw + (size_t)(col0 + r) * K + sc * 8);
  }

  for (int kt = 0; kt < NT; ++kt) {
    __syncthreads();
#pragma unroll
    for (int i = 0; i < 4; ++i) {
      int r = i * 32 + sr;
      int c = (sc ^ (r & 7)) * 8;
      *reinterpret_cast<bf16x8*>(&lA[r * 64 + c]) = ra[i];
    }
#pragma unroll
    for (int i = 0; i < BNF; ++i) {
      int r = i * 32 + sr;
      int c = (sc ^ (r & 7)) * 8;
      *reinterpret_cast<bf16x8*>(&lB[r * 64 + c]) = rb[i];
    }
    __syncthreads();
    if (kt + 1 < NT) {
      int k0 = (kt + 1) << 6;
#pragma unroll
      for (int i = 0; i < 4; ++i) {
        int r = i * 32 + sr;
        ra[i] = *reinterpret_cast<const bf16x8*>(A + (size_t)(row0 + r) * K + k0 + sc * 8);
      }
#pragma unroll
      for (int i = 0; i < BNF; ++i) {
        int r = i * 32 + sr;
        rb[i] = *reinterpret_cast<const bf16x8*>(Bw + (size_t)(col0 + r) * K + k0 + sc * 8);
      }
    }
#pragma unroll
    for (int kk = 0; kk < 2; ++kk) {
      bf16x8 af[4], bfr[BNF];
#pragma unroll
      for (int mf = 0; mf < 4; ++mf) {
        int r = wm + mf * 16 + r16;
        int c = ((kk * 4 + g4) ^ (r & 7)) * 8;
        af[mf] = *reinterpret_cast<const bf16x8*>(&lA[r * 64 + c]);
      }
#pragma unroll
      for (int nf = 0; nf < BNF; ++nf) {
        int r = wn2 + nf * 16 + r16;
        int c = ((kk * 4 + g4) ^ (r & 7)) * 8;
        bfr[nf] = *reinterpret_cast<const bf16x8*>(&lB[r * 64 + c]);
      }
#pragma unroll
      for (int mf = 0; mf < 4; ++mf)
#pragma unroll
        for (int nf = 0; nf < BNF; ++nf)
          acc[mf][nf] =
              __builtin_amdgcn_mfma_f32_16x16x32_bf16(af[mf], bfr[nf], acc[mf][nf], 0, 0, 0);
    }
  }

#pragma unroll
  for (int mf = 0; mf < 4; ++mf)
#pragma unroll
    for (int nf = 0; nf < BNF; ++nf)
#pragma unroll
      for (int r = 0; r < 4; ++r) {
        size_t row = (size_t)(row0 + wm + mf * 16 + g4 * 4 + r);
        size_t col = (size_t)(col0 + wn2 + nf * 16 + r16);
        float v = acc[mf][nf][r];
        if (OUT_F32)
          reinterpret_cast<float*>(Cout)[row * N + col] = v;
        else
          reinterpret_cast<u16*>(Cout)[row * N + col] = f2bf(v);
      }
}

// ---------------------------------------------------------------- flash attention (r14, proven)
__global__ __launch_bounds__(512, 4) void attn_fwd10(const u16* __restrict__ Q,
                                                     const u16* __restrict__ Kf,
                                                     const u16* __restrict__ Vf,
                                                     u16* __restrict__ Oa) {
  __shared__ alignas(16) u16 arena[32768];
  const int tid = threadIdx.x;
  const int w = tid >> 6, lane = tid & 63;
  const int g = w & 3, spl = w >> 2;
  const int l31 = lane & 31, hi = lane >> 5;

  const int fid = blockIdx.x;
  const int xcd = fid & 7, idx = fid >> 3;  // xcd == (b,kvh)
  const int b = xcd >> 2, kvh = xcd & 3;
  const int h = kvh * 4 + g;
  const int t0 = idx * 32;
  const size_t bh = (size_t)(b * KVH + kvh);

  const int rg = w & 3;
  const int sv = rg & 1, isV = rg >> 1;
  const u16* gsrc = (isV ? Vf : Kf) + bh * KVSZ + sv * 65536 + spl * 2048 + lane * 8;
  const int ldst0 = isV * 16384 + sv * 4096 + spl * 2048;

  const u16* Qh = Q + ((size_t)(b * QH + h) * Tt + t0 + l31) * HD + hi * 8;
  bf16x8 qf[4];
#pragma unroll
  for (int kf = 0; kf < 4; ++kf)
    qf[kf] = *reinterpret_cast<const bf16x8*>(Qh + kf * 16);

  f32x16 oacc[2];
#pragma unroll
  for (int df = 0; df < 2; ++df)
#pragma unroll
    for (int r = 0; r < 16; ++r) oacc[df][r] = 0.f;
  float lp = 0.f;

#pragma unroll
  for (int i = 0; i < 4; ++i) gld16(gsrc + i * 512, &arena[ldst0 + i * 512]);
  __syncthreads();

  int cur = 0;
  for (int it = 0; it < 16; ++it) {
    if (it < 15) {
      const u16* gs = gsrc + (it + 1) * 4096;
      u16* ld = &arena[ldst0 + (cur ^ 1) * 8192];
#pragma unroll
      for (int i = 0; i < 4; ++i) gld16(gs + i * 512, ld + i * 512);
    }
    const int ktb = cur * 8192 + spl * 4096;
    const int vtb = 16384 + cur * 8192 + spl * 4096;

    f32x16 sacc[2];
#pragma unroll
    for (int sb = 0; sb < 2; ++sb) {
      bf16x8 kfr[4];
#pragma unroll
      for (int kf = 0; kf < 4; ++kf)
        kfr[kf] = *reinterpret_cast<const bf16x8*>(&arena[ktb + sb * 2048 + kf * 512 + lane * 8]);
#pragma unroll
      for (int r = 0; r < 16; ++r) sacc[sb][r] = 0.f;
      __builtin_amdgcn_s_setprio(1);
#pragma unroll
      for (int kf = 0; kf < 4; ++kf)
        sacc[sb] = __builtin_amdgcn_mfma_f32_32x32x16_bf16(kfr[kf], qf[kf], sacc[sb], 0, 0, 0);
      __builtin_amdgcn_s_setprio(0);
    }

    float a0 = 0.f, a1 = 0.f, a2 = 0.f, a3 = 0.f;
#pragma unroll
    for (int sb = 0; sb < 2; ++sb)
#pragma unroll
      for (int r = 0; r < 16; r += 4) {
        float e0 = exp2r(sacc[sb][r]);
        float e1 = exp2r(sacc[sb][r + 1]);
        float e2 = exp2r(sacc[sb][r + 2]);
        float e3 = exp2r(sacc[sb][r + 3]);
        sacc[sb][r] = e0; sacc[sb][r + 1] = e1; sacc[sb][r + 2] = e2; sacc[sb][r + 3] = e3;
        a0 += e0; a1 += e1; a2 += e2; a3 += e3;
      }
    lp += (a0 + a1) + (a2 + a3);

    bf16x8 pf[2][2];
#pragma unroll
    for (int sb = 0; sb < 2; ++sb) {
      u32 pw[8];
#pragma unroll
      for (int r2 = 0; r2 < 8; ++r2) {
        u32 o;
        asm("v_cvt_pk_bf16_f32 %0, %1, %2"
            : "=v"(o)
            : "v"(sacc[sb][2 * r2]), "v"(sacc[sb][2 * r2 + 1]));
        pw[r2] = o;
      }
      u32 fw[2][4];
#pragma unroll
      for (int pp = 0; pp < 4; ++pp) {
        int ks = pp >> 1, o = pp & 1;
        u32 a = pw[ks * 4 + o], bq = pw[ks * 4 + o + 2];
        asm("v_permlane32_swap_b32 %0, %1" : "+v"(a), "+v"(bq));
        fw[ks][o] = a;
        fw[ks][o + 2] = bq;
      }
#pragma unroll
      for (int ks = 0; ks < 2; ++ks) {
        i32x4 iv = {(int)fw[ks][0], (int)fw[ks][1], (int)fw[ks][2], (int)fw[ks][3]};
        pf[sb][ks] = __builtin_bit_cast(bf16x8, iv);
      }
    }

    __builtin_amdgcn_s_setprio(1);
#pragma unroll
    for (int df = 0; df < 2; ++df)
#pragma unroll
      for (int sb = 0; sb < 2; ++sb)
#pragma unroll
        for (int ks = 0; ks < 2; ++ks) {
          bf16x8 vfr = *reinterpret_cast<const bf16x8*>(
              &arena[vtb + (df * 4 + sb * 2 + ks) * 512 + lane * 8]);
          oacc[df] = __builtin_amdgcn_mfma_f32_32x32x16_bf16(vfr, pf[sb][ks], oacc[df], 0, 0, 0);
        }
    __builtin_amdgcn_s_setprio(0);

    __syncthreads();
    cur ^= 1;
  }

  lp += __shfl_xor(lp, 32);
  float* cb = reinterpret_cast<float*>(arena) + ((size_t)g * 32 + l31) * 66;
  if (spl == 1) {
#pragma unroll
    for (int df = 0; df < 2; ++df)
#pragma unroll
      for (int r = 0; r < 16; ++r) {
        int d = df * 32 + (r & 3) + 8 * (r >> 2) + 4 * hi;
        cb[d] = oacc[df][r];
      }
    if (hi == 0) cb[64] = lp;
  }
  __syncthreads();
  if (spl == 0) {
    lp += cb[64];
    float linv = 1.0f / lp;
    u16* otg = arena + 17408 + g * 2304;
#pragma unroll
    for (int df = 0; df < 2; ++df)
#pragma unroll
      for (int r = 0; r < 16; ++r) {
        int d = df * 32 + (r & 3) + 8 * (r >> 2) + 4 * hi;
        otg[l31 * 72 + d] = f2bf((oacc[df][r] + cb[d]) * linv);
      }
  }
  __syncthreads();
  if (spl == 0) {
    const u16* otg = arena + 17408 + g * 2304;
    int tr = lane >> 1, dblk = (lane & 1) * 32;
    u16* gdst = Oa + ((size_t)(b * Tt + t0 + tr)) * Dd + h * HD + dblk;
#pragma unroll
    for (int c = 0; c < 4; ++c) {
      ushort8v vv = *reinterpret_cast<const ushort8v*>(&otg[tr * 72 + dblk + c * 8]);
      *reinterpret_cast<ushort8v*>(gdst + c * 8) = vv;
    }
  }
}

// ---------------------------------------------------------------- launch
extern "C" void kernel_launch(void* const* d_in, const int* in_sizes, int n_in, void* d_out,
                              int out_size, void* d_ws, size_t ws_size, hipStream_t stream) {
  (void)in_sizes; (void)n_in; (void)out_size; (void)ws_size;
  const float* x = (const float*)d_in[0];
  const float* cosT = (const float*)d_in[1];
  const float* sinT = (const float*)d_in[2];
  const float* Wq = (const float*)d_in[3];
  const float* Wkv = (const float*)d_in[4];
  const float* Wo = (const float*)d_in[5];

  char* p = (char*)d_ws;
  u16* xb = (u16*)p;   p += (size_t)4096 * 1024 * 2;
  u16* wqkv = (u16*)p; p += (size_t)1536 * 1024 * 2;
  u16* wob = (u16*)p;  p += (size_t)1024 * 1024 * 2;
  u16* Pbuf = (u16*)p; p += (size_t)4096 * 1536 * 2;
  u16* Qb = (u16*)p;   p += (size_t)Bb * QH * Tt * HD * 2;
  u16* Kbuf = (u16*)p; p += (size_t)Bb * KVH * Tt * HD * 2;
  u16* Vfb = (u16*)p;  p += (size_t)Bb * KVH * HD * Tt * 2;
  u16* Ob = Pbuf;  // attention-output staging (bf16), feeds gemm2

  cvt_all<<<6656, 256, 0, stream>>>(x, Wq, Wkv, Wo, xb, wqkv, wob);
  gemm_qkv<<<768, 256, 0, stream>>>(xb, wqkv, cosT, sinT, Qb, Kbuf, Vfb);
  attn_fwd10<<<512, 512, 0, stream>>>(Qb, Kbuf, Vfb, Ob);
  gemm_bt<true, 2><<<512, 256, 0, stream>>>(Ob, wob, d_out, 4096, 1024, 1024);
}